// Round 9
// baseline (411.051 us; speedup 1.0000x reference)
//
#include <hip/hip_runtime.h>

#define N_NODES 50000
#define IN_DIM 64
#define OUT_DIM 128
#define N_EDGES 800000

#define NBLK 128                    // partition blocks
#define EPB (N_EDGES / NBLK)        // 6250 edges per block (exact)
#define NBUCK 196                   // ceil(50000/256) buckets of 256 dsts
#define NSTRIP (N_NODES / 16)       // 3125 16-node strips (exact)
#define WLDS 136                    // padded bf16 row stride: bank step 4 -> 2-way (free)

typedef __attribute__((ext_vector_type(8))) short bf16x8;
typedef __attribute__((ext_vector_type(4))) float f32x4;

__device__ __forceinline__ unsigned short f2bf(float f) {
    unsigned u = __float_as_uint(f);
    unsigned r = u + 0x7FFFu + ((u >> 16) & 1u);   // round-to-nearest-even
    return (unsigned short)(r >> 16);
}

// ---------------- A0: per-(block,bucket) histogram + x->bf16 + W2->bf16 ----------------
__global__ __launch_bounds__(256) void bucket_count_cvt(const int* __restrict__ ei,
                                                        const float* __restrict__ x,
                                                        const float* __restrict__ Wl,
                                                        const float* __restrict__ Wr,
                                                        int* __restrict__ cnt_mat,
                                                        unsigned short* __restrict__ xh,
                                                        unsigned short* __restrict__ w2h)
{
    __shared__ int h[NBUCK];
    int t = threadIdx.x, blk = blockIdx.x;
    for (int i = t; i < NBUCK; i += 256) h[i] = 0;
    __syncthreads();
    int s = blk * EPB;
    for (int i = s + t; i < s + EPB; i += 256)
        atomicAdd(&h[ei[N_EDGES + i] >> 8], 1);
    // fused: convert this block's slice of x to bf16
    for (int i = t; i < 6250; i += 256) {
        int gi = blk * 6250 + i;
        float4 v = ((const float4*)x)[gi];
        ushort4 o;
        o.x = f2bf(v.x); o.y = f2bf(v.y); o.z = f2bf(v.z); o.w = f2bf(v.w);
        ((ushort4*)xh)[gi] = o;
    }
    // fused: W2h[o] = [Wr[o] | Wl[o]] in bf16 (block blk handles o=blk)
    if (t < 64) {
        w2h[blk * 128 + t]      = f2bf(Wr[blk * 64 + t]);
        w2h[blk * 128 + 64 + t] = f2bf(Wl[blk * 64 + t]);
    }
    __syncthreads();
    for (int b = t; b < NBUCK; b += 256) cnt_mat[b * NBLK + blk] = h[b];
}

// ---------------- scan: each block redundantly computes bucket starts in LDS;
// its 4 waves then scan their cnt_mat rows into per-(bucket,block) cursors.
__global__ __launch_bounds__(256) void rowscan(int* __restrict__ cnt_mat)
{
    __shared__ int tot[NBUCK];
    __shared__ int bst[NBUCK];
    __shared__ int ws[4];
    int t = threadIdx.x, lane = t & 63, wid = t >> 6;
    if (t < NBUCK) {
        const int4* row = (const int4*)(cnt_mat + t * NBLK);
        int sum = 0;
#pragma unroll 8
        for (int i = 0; i < NBLK / 4; ++i) { int4 v = row[i]; sum += v.x + v.y + v.z + v.w; }
        tot[t] = sum;
    }
    __syncthreads();
    int v = (t < NBUCK) ? tot[t] : 0;
    int incl = v;
#pragma unroll
    for (int d = 1; d < 64; d <<= 1) {
        int u = __shfl_up(incl, d, 64);
        if (lane >= d) incl += u;
    }
    if (lane == 63) ws[wid] = incl;
    __syncthreads();
    int woff = 0;
    for (int w = 0; w < wid; ++w) woff += ws[w];
    if (t < NBUCK) bst[t] = woff + incl - v;
    __syncthreads();
    int b = blockIdx.x * 4 + wid;
    if (b >= NBUCK) return;
    int base = bst[b];
#pragma unroll
    for (int c = 0; c < 2; ++c) {
        int idx = c * 64 + lane;
        int cv = cnt_mat[b * NBLK + idx];
        int ic = cv;
#pragma unroll
        for (int d = 1; d < 64; d <<= 1) {
            int u = __shfl_up(ic, d, 64);
            if (lane >= d) ic += u;
        }
        cnt_mat[b * NBLK + idx] = base + ic - cv;
        base += __shfl(ic, 63, 64);
    }
}

// ---------------- A1: partition edges into bucket-contiguous packed ebuf ----------------
// pack = src (16b) | dst_local (8b) << 16   (src < 50000 < 65536)
__global__ __launch_bounds__(256) void bucket_place(const int* __restrict__ ei,
                                                    const int* __restrict__ cnt_scan,
                                                    unsigned* __restrict__ ebuf)
{
    __shared__ int cur[NBUCK];
    int t = threadIdx.x, blk = blockIdx.x;
    for (int b = t; b < NBUCK; b += 256) cur[b] = cnt_scan[b * NBLK + blk];
    __syncthreads();
    int s = blk * EPB;
    for (int i = s + t; i < s + EPB; i += 256) {
        int src = ei[i], dst = ei[N_EDGES + i];
        int slot = atomicAdd(&cur[dst >> 8], 1);
        ebuf[slot] = (unsigned)src | ((unsigned)(dst & 255) << 16);
    }
}

// ---------------- gather: one block per bucket, edge-parallel, LDS f32 accumulators ----
// acc[256 nodes][64 features] in LDS (64 KB). Per edge: 64 lanes = 64 features,
// one global 128B row read + one ds_add_f32 (banks lane%32 -> 2-way, free).
// 16 waves stride the bucket's edge range; 8-edge unroll keeps 8 row loads in flight.
__global__ __launch_bounds__(1024) void gather_lds(const unsigned short* __restrict__ xh,
                                                   const int* __restrict__ cnt_scan,
                                                   const unsigned* __restrict__ ebuf,
                                                   unsigned short* __restrict__ meanh)
{
    __shared__ float acc[256 * 64];     // 64 KB
    __shared__ int dcnt[256];
    __shared__ int range_s[2];
    int t = threadIdx.x, b = blockIdx.x;
    int lane = t & 63, w = t >> 6;      // 16 waves

    if (t == 0) {
        range_s[0] = cnt_scan[b * NBLK];
        range_s[1] = (b < NBUCK - 1) ? cnt_scan[(b + 1) * NBLK] : N_EDGES;
    }
#pragma unroll
    for (int i = 0; i < 16; ++i) acc[i * 1024 + t] = 0.f;
    if (t < 256) dcnt[t] = 0;
    __syncthreads();

    int bs = range_s[0], be = range_s[1];

    // degree histogram (edge-strided, all lanes parallel)
    for (int e = bs + t; e < be; e += 1024)
        atomicAdd(&dcnt[(ebuf[e] >> 16) & 255], 1);

    // feature accumulation: wave w takes 64-edge chunks strided by 16 waves
    for (int e0 = bs + w * 64; e0 < be; e0 += 1024) {
        int m = be - e0; if (m > 64) m = 64;
        unsigned pv = (lane < m) ? ebuf[e0 + lane] : 0u;
        int k = 0;
        for (; k + 8 <= m; k += 8) {
            unsigned p[8]; float f[8];
#pragma unroll
            for (int u = 0; u < 8; ++u) p[u] = __shfl(pv, k + u, 64);
#pragma unroll
            for (int u = 0; u < 8; ++u) {
                int src = p[u] & 0xFFFF;
                unsigned short hv = xh[(size_t)src * IN_DIM + lane];
                f[u] = __uint_as_float((unsigned)hv << 16);
            }
#pragma unroll
            for (int u = 0; u < 8; ++u)
                atomicAdd(&acc[((p[u] >> 16) & 255) * 64 + lane], f[u]);
        }
        for (; k < m; ++k) {
            unsigned p = __shfl(pv, k, 64);
            int src = p & 0xFFFF;
            unsigned short hv = xh[(size_t)src * IN_DIM + lane];
            atomicAdd(&acc[((p >> 16) & 255) * 64 + lane],
                      __uint_as_float((unsigned)hv << 16));
        }
    }
    __syncthreads();

    // finalize: mean = acc/deg, write bf16 packed pairs (coalesced u32 stores)
    for (int i = t; i < 256 * 32; i += 1024) {
        int nd = i >> 5, fp = i & 31;
        int node = b * 256 + nd;
        if (node >= N_NODES) continue;
        int deg = dcnt[nd];
        float inv = deg ? 1.0f / (float)deg : 0.0f;
        float m0 = acc[nd * 64 + fp * 2] * inv;
        float m1 = acc[nd * 64 + fp * 2 + 1] * inv;
        unsigned mh = (unsigned)f2bf(m0) | ((unsigned)f2bf(m1) << 16);
        *(unsigned*)(meanh + (size_t)node * IN_DIM + fp * 2) = mh;
    }
}

// ---------------- MFMA linear: out = [xh|meanh] @ W2h^T + b ----------------
__global__ __launch_bounds__(256) void sage_mfma(
    const unsigned short* __restrict__ xh, const unsigned short* __restrict__ meanh,
    const unsigned short* __restrict__ w2h, const float* __restrict__ bl,
    float* __restrict__ out)
{
    __shared__ unsigned short wlds[128 * WLDS];   // 34.8 KB
    int t = threadIdx.x;
#pragma unroll
    for (int c = 0; c < 8; ++c) {
        int idx = c * 256 + t;          // 2048 chunks of 8 bf16
        int o = idx >> 4, kc = idx & 15;
        bf16x8 v = *(const bf16x8*)(w2h + o * 128 + kc * 8);
        *(bf16x8*)(&wlds[o * WLDS + kc * 8]) = v;
    }
    __syncthreads();

    int wid = t >> 6, lane = t & 63;
    int strip = blockIdx.x * 4 + wid;
    if (strip >= NSTRIP) return;
    int nbase = strip * 16;
    int row = lane & 15, q = lane >> 4;

    const unsigned short* xrow = xh    + (size_t)(nbase + row) * IN_DIM + q * 8;
    const unsigned short* mrow = meanh + (size_t)(nbase + row) * IN_DIM + q * 8;
    bf16x8 a[4];
    a[0] = *(const bf16x8*)(xrow);
    a[1] = *(const bf16x8*)(xrow + 32);
    a[2] = *(const bf16x8*)(mrow);
    a[3] = *(const bf16x8*)(mrow + 32);

    f32x4 acc[8];
#pragma unroll
    for (int ot = 0; ot < 8; ++ot) acc[ot] = (f32x4){0.f, 0.f, 0.f, 0.f};

#pragma unroll
    for (int ot = 0; ot < 8; ++ot) {
        const unsigned short* wb = &wlds[(ot * 16 + row) * WLDS + q * 8];
#pragma unroll
        for (int s = 0; s < 4; ++s) {
            bf16x8 bfrag = *(const bf16x8*)(wb + s * 32);
            acc[ot] = __builtin_amdgcn_mfma_f32_16x16x32_bf16(a[s], bfrag, acc[ot], 0, 0, 0);
        }
    }

#pragma unroll
    for (int ot = 0; ot < 8; ++ot) {
        float bias = bl[ot * 16 + row];
#pragma unroll
        for (int r = 0; r < 4; ++r) {
            int n = nbase + q * 4 + r;
            out[(size_t)n * OUT_DIM + ot * 16 + row] = acc[ot][r] + bias;
        }
    }
}

extern "C" void kernel_launch(void* const* d_in, const int* in_sizes, int n_in,
                              void* d_out, int out_size, void* d_ws, size_t ws_size,
                              hipStream_t stream) {
    const float* x  = (const float*)d_in[0];
    const int*   ei = (const int*)d_in[1];
    const float* Wl = (const float*)d_in[2];
    const float* bl = (const float*)d_in[3];
    const float* Wr = (const float*)d_in[4];
    float* out = (float*)d_out;

    // ws layout (~16.1 MB):
    int*            cnt_mat = (int*)d_ws;                               // 25088 ints
    unsigned*       ebuf    = (unsigned*)(cnt_mat + NBUCK * NBLK);      // 800000 uints
    unsigned short* xh      = (unsigned short*)(ebuf + N_EDGES);        // 3.2M bf16
    unsigned short* meanh   = xh + (size_t)N_NODES * IN_DIM;            // 3.2M bf16
    unsigned short* w2h     = meanh + (size_t)N_NODES * IN_DIM;         // 16384 bf16

    bucket_count_cvt<<<NBLK, 256, 0, stream>>>(ei, x, Wl, Wr, cnt_mat, xh, w2h);
    rowscan<<<(NBUCK + 3) / 4, 256, 0, stream>>>(cnt_mat);
    bucket_place<<<NBLK, 256, 0, stream>>>(ei, cnt_mat, ebuf);
    gather_lds<<<NBUCK, 1024, 0, stream>>>(xh, cnt_mat, ebuf, meanh);

    int mb = (NSTRIP + 3) / 4;                      // 782
    sage_mfma<<<mb, 256, 0, stream>>>(xh, meanh, w2h, bl, out);
}

// Round 10
// 81.001 us; speedup vs baseline: 5.0746x; 5.0746x over previous
//
#include <hip/hip_runtime.h>

#define N_NODES 50000
#define IN_DIM 64
#define OUT_DIM 128
#define N_EDGES 800000

#define NBLK 128                    // partition blocks
#define EPB (N_EDGES / NBLK)        // 6250 edges per block (exact)
#define NBUCK 196                   // ceil(50000/256) buckets of 256 dsts
#define NSTRIP (N_NODES / 16)       // 3125 16-node strips (exact)
#define WLDS 136                    // padded bf16 row stride: bank step 4 -> 2-way (free)

typedef __attribute__((ext_vector_type(8))) short bf16x8;
typedef __attribute__((ext_vector_type(4))) float f32x4;

__device__ __forceinline__ unsigned short f2bf(float f) {
    unsigned u = __float_as_uint(f);
    unsigned r = u + 0x7FFFu + ((u >> 16) & 1u);   // round-to-nearest-even
    return (unsigned short)(r >> 16);
}

// ---------------- A0: per-(block,bucket) histogram + x->bf16 + W2->bf16 ----------------
__global__ __launch_bounds__(256) void bucket_count_cvt(const int* __restrict__ ei,
                                                        const float* __restrict__ x,
                                                        const float* __restrict__ Wl,
                                                        const float* __restrict__ Wr,
                                                        int* __restrict__ cnt_mat,
                                                        unsigned short* __restrict__ xh,
                                                        unsigned short* __restrict__ w2h)
{
    __shared__ int h[NBUCK];
    int t = threadIdx.x, blk = blockIdx.x;
    for (int i = t; i < NBUCK; i += 256) h[i] = 0;
    __syncthreads();
    int s = blk * EPB;
    for (int i = s + t; i < s + EPB; i += 256)
        atomicAdd(&h[ei[N_EDGES + i] >> 8], 1);
    // fused: convert this block's slice of x to bf16
    for (int i = t; i < 6250; i += 256) {
        int gi = blk * 6250 + i;
        float4 v = ((const float4*)x)[gi];
        ushort4 o;
        o.x = f2bf(v.x); o.y = f2bf(v.y); o.z = f2bf(v.z); o.w = f2bf(v.w);
        ((ushort4*)xh)[gi] = o;
    }
    // fused: W2h[o] = [Wr[o] | Wl[o]] in bf16 (block blk handles o=blk)
    if (t < 64) {
        w2h[blk * 128 + t]      = f2bf(Wr[blk * 64 + t]);
        w2h[blk * 128 + 64 + t] = f2bf(Wl[blk * 64 + t]);
    }
    __syncthreads();
    for (int b = t; b < NBUCK; b += 256) cnt_mat[b * NBLK + blk] = h[b];
}

// ---------------- scan: each block redundantly computes bucket starts in LDS;
// its 4 waves then scan their cnt_mat rows into per-(bucket,block) cursors.
__global__ __launch_bounds__(256) void rowscan(int* __restrict__ cnt_mat)
{
    __shared__ int tot[NBUCK];
    __shared__ int bst[NBUCK];
    __shared__ int ws[4];
    int t = threadIdx.x, lane = t & 63, wid = t >> 6;
    if (t < NBUCK) {
        const int4* row = (const int4*)(cnt_mat + t * NBLK);
        int sum = 0;
#pragma unroll 8
        for (int i = 0; i < NBLK / 4; ++i) { int4 v = row[i]; sum += v.x + v.y + v.z + v.w; }
        tot[t] = sum;
    }
    __syncthreads();
    int v = (t < NBUCK) ? tot[t] : 0;
    int incl = v;
#pragma unroll
    for (int d = 1; d < 64; d <<= 1) {
        int u = __shfl_up(incl, d, 64);
        if (lane >= d) incl += u;
    }
    if (lane == 63) ws[wid] = incl;
    __syncthreads();
    int woff = 0;
    for (int w = 0; w < wid; ++w) woff += ws[w];
    if (t < NBUCK) bst[t] = woff + incl - v;
    __syncthreads();
    int b = blockIdx.x * 4 + wid;
    if (b >= NBUCK) return;
    int base = bst[b];
#pragma unroll
    for (int c = 0; c < 2; ++c) {
        int idx = c * 64 + lane;
        int cv = cnt_mat[b * NBLK + idx];
        int ic = cv;
#pragma unroll
        for (int d = 1; d < 64; d <<= 1) {
            int u = __shfl_up(ic, d, 64);
            if (lane >= d) ic += u;
        }
        cnt_mat[b * NBLK + idx] = base + ic - cv;
        base += __shfl(ic, 63, 64);
    }
}

// ---------------- A1: partition edges into bucket-contiguous packed ebuf ----------------
// pack = src (16b) | dst_local (8b) << 16   (src < 50000 < 65536)
__global__ __launch_bounds__(256) void bucket_place(const int* __restrict__ ei,
                                                    const int* __restrict__ cnt_scan,
                                                    unsigned* __restrict__ ebuf)
{
    __shared__ int cur[NBUCK];
    int t = threadIdx.x, blk = blockIdx.x;
    for (int b = t; b < NBUCK; b += 256) cur[b] = cnt_scan[b * NBLK + blk];
    __syncthreads();
    int s = blk * EPB;
    for (int i = s + t; i < s + EPB; i += 256) {
        int src = ei[i], dst = ei[N_EDGES + i];
        int slot = atomicAdd(&cur[dst >> 8], 1);
        ebuf[slot] = (unsigned)src | ((unsigned)(dst & 255) << 16);
    }
}

// ---------------- B: final CSR within each bucket (1 block per bucket) ----------------
__global__ __launch_bounds__(256) void bucket_bin(const unsigned* __restrict__ ebuf,
                                                  const int* __restrict__ cnt_scan,
                                                  unsigned short* __restrict__ srcs,
                                                  int* __restrict__ offs)
{
    __shared__ int h[256];
    __shared__ int ws2[4];
    __shared__ int range_s[2];
    int t = threadIdx.x, b = blockIdx.x;
    int lane = t & 63, wid = t >> 6;
    if (t == 0) {
        range_s[0] = cnt_scan[b * NBLK];
        range_s[1] = (b < NBUCK - 1) ? cnt_scan[(b + 1) * NBLK] : N_EDGES;
    }
    h[t] = 0;
    __syncthreads();
    int bs = range_s[0], be = range_s[1];
    for (int i = bs + t; i < be; i += 256)
        atomicAdd(&h[(ebuf[i] >> 16) & 255], 1);
    __syncthreads();
    int v = h[t];
    int incl = v;
#pragma unroll
    for (int d = 1; d < 64; d <<= 1) {
        int u = __shfl_up(incl, d, 64);
        if (lane >= d) incl += u;
    }
    if (lane == 63) ws2[wid] = incl;
    __syncthreads();
    int woff = 0;
    for (int w = 0; w < wid; ++w) woff += ws2[w];
    incl += woff;
    int ex = incl - v;
    h[t] = bs + ex;
    int node = b * 256 + t;
    if (node < N_NODES) offs[node] = bs + incl;
    __syncthreads();
    for (int i = bs + t; i < be; i += 256) {
        unsigned p = ebuf[i];
        int pos = atomicAdd(&h[(p >> 16) & 255], 1);
        srcs[pos] = (unsigned short)(p & 0xFFFFu);
    }
}

// ---------------- gather + mean: wave per node, 4 edges per wave-load ----------------
// Row = 64 bf16 = 128 B = 16 lanes x ushort4 (8B). quarter q = lane>>4 picks the
// edge within a group of 4; fl = lane&15 picks the feature quad. A 16-edge
// unrolled group issues 4 independent 8B-per-lane loads (16 edges in flight).
// Reduce across quarters via 2 shfl_xor; lanes 0-15 write the 8B packed mean.
__global__ __launch_bounds__(256) void gather_bf16(const unsigned short* __restrict__ xh,
                                                   const int* __restrict__ offs,
                                                   const unsigned short* __restrict__ srcs,
                                                   unsigned short* __restrict__ meanh)
{
    int n = (blockIdx.x * 256 + threadIdx.x) >> 6;
    int lane = threadIdx.x & 63;
    if (n >= N_NODES) return;
    int q = lane >> 4;          // 0..3: edge slot within group-of-4
    int fl = lane & 15;         // feature quad: features 4*fl .. 4*fl+3
    int end = offs[n];
    int start = n ? offs[n - 1] : 0;
    float a0 = 0.f, a1 = 0.f, a2 = 0.f, a3 = 0.f;
    for (int j = start; j < end; j += 64) {
        int m = end - j; if (m > 64) m = 64;
        int sv = (lane < m) ? (int)srcs[j + lane] : 0;
        for (int k = 0; k < m; k += 16) {
            int e0 = k + q, e1 = k + 4 + q, e2 = k + 8 + q, e3 = k + 12 + q;
            int s0 = __shfl(sv, e0, 64);
            int s1 = __shfl(sv, e1, 64);
            int s2 = __shfl(sv, e2, 64);
            int s3 = __shfl(sv, e3, 64);
            ushort4 r0 = *(const ushort4*)(xh + (size_t)s0 * IN_DIM + fl * 4);
            ushort4 r1 = *(const ushort4*)(xh + (size_t)s1 * IN_DIM + fl * 4);
            ushort4 r2 = *(const ushort4*)(xh + (size_t)s2 * IN_DIM + fl * 4);
            ushort4 r3 = *(const ushort4*)(xh + (size_t)s3 * IN_DIM + fl * 4);
            if (e0 < m) {
                a0 += __uint_as_float((unsigned)r0.x << 16);
                a1 += __uint_as_float((unsigned)r0.y << 16);
                a2 += __uint_as_float((unsigned)r0.z << 16);
                a3 += __uint_as_float((unsigned)r0.w << 16);
            }
            if (e1 < m) {
                a0 += __uint_as_float((unsigned)r1.x << 16);
                a1 += __uint_as_float((unsigned)r1.y << 16);
                a2 += __uint_as_float((unsigned)r1.z << 16);
                a3 += __uint_as_float((unsigned)r1.w << 16);
            }
            if (e2 < m) {
                a0 += __uint_as_float((unsigned)r2.x << 16);
                a1 += __uint_as_float((unsigned)r2.y << 16);
                a2 += __uint_as_float((unsigned)r2.z << 16);
                a3 += __uint_as_float((unsigned)r2.w << 16);
            }
            if (e3 < m) {
                a0 += __uint_as_float((unsigned)r3.x << 16);
                a1 += __uint_as_float((unsigned)r3.y << 16);
                a2 += __uint_as_float((unsigned)r3.z << 16);
                a3 += __uint_as_float((unsigned)r3.w << 16);
            }
        }
    }
    // reduce across the 4 quarters (feature fl held by lanes fl, fl+16, fl+32, fl+48)
    a0 += __shfl_xor(a0, 16, 64); a1 += __shfl_xor(a1, 16, 64);
    a2 += __shfl_xor(a2, 16, 64); a3 += __shfl_xor(a3, 16, 64);
    a0 += __shfl_xor(a0, 32, 64); a1 += __shfl_xor(a1, 32, 64);
    a2 += __shfl_xor(a2, 32, 64); a3 += __shfl_xor(a3, 32, 64);
    int deg = end - start;
    float inv = deg ? 1.0f / (float)deg : 0.0f;
    if (lane < 16) {
        ushort4 mh;
        mh.x = f2bf(a0 * inv); mh.y = f2bf(a1 * inv);
        mh.z = f2bf(a2 * inv); mh.w = f2bf(a3 * inv);
        *(ushort4*)(meanh + (size_t)n * IN_DIM + fl * 4) = mh;
    }
}

// ---------------- MFMA linear: out = [xh|meanh] @ W2h^T + b ----------------
__global__ __launch_bounds__(256) void sage_mfma(
    const unsigned short* __restrict__ xh, const unsigned short* __restrict__ meanh,
    const unsigned short* __restrict__ w2h, const float* __restrict__ bl,
    float* __restrict__ out)
{
    __shared__ unsigned short wlds[128 * WLDS];   // 34.8 KB
    int t = threadIdx.x;
#pragma unroll
    for (int c = 0; c < 8; ++c) {
        int idx = c * 256 + t;          // 2048 chunks of 8 bf16
        int o = idx >> 4, kc = idx & 15;
        bf16x8 v = *(const bf16x8*)(w2h + o * 128 + kc * 8);
        *(bf16x8*)(&wlds[o * WLDS + kc * 8]) = v;
    }
    __syncthreads();

    int wid = t >> 6, lane = t & 63;
    int strip = blockIdx.x * 4 + wid;
    if (strip >= NSTRIP) return;
    int nbase = strip * 16;
    int row = lane & 15, q = lane >> 4;

    const unsigned short* xrow = xh    + (size_t)(nbase + row) * IN_DIM + q * 8;
    const unsigned short* mrow = meanh + (size_t)(nbase + row) * IN_DIM + q * 8;
    bf16x8 a[4];
    a[0] = *(const bf16x8*)(xrow);
    a[1] = *(const bf16x8*)(xrow + 32);
    a[2] = *(const bf16x8*)(mrow);
    a[3] = *(const bf16x8*)(mrow + 32);

    f32x4 acc[8];
#pragma unroll
    for (int ot = 0; ot < 8; ++ot) acc[ot] = (f32x4){0.f, 0.f, 0.f, 0.f};

#pragma unroll
    for (int ot = 0; ot < 8; ++ot) {
        const unsigned short* wb = &wlds[(ot * 16 + row) * WLDS + q * 8];
#pragma unroll
        for (int s = 0; s < 4; ++s) {
            bf16x8 bfrag = *(const bf16x8*)(wb + s * 32);
            acc[ot] = __builtin_amdgcn_mfma_f32_16x16x32_bf16(a[s], bfrag, acc[ot], 0, 0, 0);
        }
    }

#pragma unroll
    for (int ot = 0; ot < 8; ++ot) {
        float bias = bl[ot * 16 + row];
#pragma unroll
        for (int r = 0; r < 4; ++r) {
            int n = nbase + q * 4 + r;
            out[(size_t)n * OUT_DIM + ot * 16 + row] = acc[ot][r] + bias;
        }
    }
}

extern "C" void kernel_launch(void* const* d_in, const int* in_sizes, int n_in,
                              void* d_out, int out_size, void* d_ws, size_t ws_size,
                              hipStream_t stream) {
    const float* x  = (const float*)d_in[0];
    const int*   ei = (const int*)d_in[1];
    const float* Wl = (const float*)d_in[2];
    const float* bl = (const float*)d_in[3];
    const float* Wr = (const float*)d_in[4];
    float* out = (float*)d_out;

    // ws layout (~17.9 MB):
    int*            cnt_mat = (int*)d_ws;                               // 25088 ints
    unsigned*       ebuf    = (unsigned*)(cnt_mat + NBUCK * NBLK);      // 800000 uints
    int*            offs    = (int*)(ebuf + N_EDGES);                   // 50000 ints
    unsigned short* xh      = (unsigned short*)(offs + N_NODES);        // 3.2M bf16
    unsigned short* meanh   = xh + (size_t)N_NODES * IN_DIM;            // 3.2M bf16
    unsigned short* w2h     = meanh + (size_t)N_NODES * IN_DIM;         // 16384 bf16
    unsigned short* srcs    = w2h + 128 * 128;                          // 800000 ushort

    bucket_count_cvt<<<NBLK, 256, 0, stream>>>(ei, x, Wl, Wr, cnt_mat, xh, w2h);
    rowscan<<<(NBUCK + 3) / 4, 256, 0, stream>>>(cnt_mat);
    bucket_place<<<NBLK, 256, 0, stream>>>(ei, cnt_mat, ebuf);
    bucket_bin<<<NBUCK, 256, 0, stream>>>(ebuf, cnt_mat, srcs, offs);

    int gb = (N_NODES * 64 + 255) / 256;            // 12500
    gather_bf16<<<gb, 256, 0, stream>>>(xh, offs, srcs, meanh);

    int mb = (NSTRIP + 3) / 4;                      // 782
    sage_mfma<<<mb, 256, 0, stream>>>(xh, meanh, w2h, bl, out);
}

// Round 11
// 79.137 us; speedup vs baseline: 5.1942x; 1.0236x over previous
//
#include <hip/hip_runtime.h>

#define N_NODES 50000
#define IN_DIM 64
#define OUT_DIM 128
#define N_EDGES 800000

#define NBLK 128                    // partition blocks
#define EPB (N_EDGES / NBLK)        // 6250 edges per block (exact)
#define NBUCK 391                   // ceil(50000/128) buckets of 128 dsts
#define WLDS 136                    // padded bf16 row stride: bank step 4 -> 2-way (free)
#define FIXSCALE 1048576.0f         // 2^20 fixed-point
#define INVFIX (1.0f / 1048576.0f)

typedef __attribute__((ext_vector_type(8))) short bf16x8;
typedef __attribute__((ext_vector_type(4))) float f32x4;

__device__ __forceinline__ unsigned short f2bf(float f) {
    unsigned u = __float_as_uint(f);
    unsigned r = u + 0x7FFFu + ((u >> 16) & 1u);   // round-to-nearest-even
    return (unsigned short)(r >> 16);
}

// ---------------- A0: per-(block,bucket) histogram + x->bf16 + W2->bf16 ----------------
__global__ __launch_bounds__(256) void bucket_count_cvt(const int* __restrict__ ei,
                                                        const float* __restrict__ x,
                                                        const float* __restrict__ Wl,
                                                        const float* __restrict__ Wr,
                                                        int* __restrict__ cnt_mat,
                                                        unsigned short* __restrict__ xh,
                                                        unsigned short* __restrict__ w2h)
{
    __shared__ int h[NBUCK];
    int t = threadIdx.x, blk = blockIdx.x;
    for (int i = t; i < NBUCK; i += 256) h[i] = 0;
    __syncthreads();
    int s = blk * EPB;
    for (int i = s + t; i < s + EPB; i += 256)
        atomicAdd(&h[ei[N_EDGES + i] >> 7], 1);
    // fused: convert this block's slice of x to bf16
    for (int i = t; i < 6250; i += 256) {
        int gi = blk * 6250 + i;
        float4 v = ((const float4*)x)[gi];
        ushort4 o;
        o.x = f2bf(v.x); o.y = f2bf(v.y); o.z = f2bf(v.z); o.w = f2bf(v.w);
        ((ushort4*)xh)[gi] = o;
    }
    // fused: W2h[o] = [Wr[o] | Wl[o]] in bf16 (block blk handles o=blk)
    if (t < 64) {
        w2h[blk * 128 + t]      = f2bf(Wr[blk * 64 + t]);
        w2h[blk * 128 + 64 + t] = f2bf(Wl[blk * 64 + t]);
    }
    __syncthreads();
    for (int b = t; b < NBUCK; b += 256) cnt_mat[b * NBLK + blk] = h[b];
}

// ---------------- scan: per-bucket totals + exclusive bucket starts (redundant per
// block), then each of the block's 4 waves scans one bucket's 128-entry row into
// per-(bucket,partition-block) cursors. grid = ceil(NBUCK/4).
__global__ __launch_bounds__(256) void rowscan(int* __restrict__ cnt_mat)
{
    __shared__ int tot[NBUCK];
    __shared__ int bst[NBUCK];
    int t = threadIdx.x, lane = t & 63, wid = t >> 6;
    for (int b = t; b < NBUCK; b += 256) {
        const int4* row = (const int4*)(cnt_mat + b * NBLK);
        int sum = 0;
#pragma unroll 8
        for (int i = 0; i < NBLK / 4; ++i) { int4 v = row[i]; sum += v.x + v.y + v.z + v.w; }
        tot[b] = sum;
    }
    __syncthreads();
    if (wid == 0) {                       // wave 0: exclusive scan of 391 totals
        int carry = 0;
        for (int base = 0; base < NBUCK; base += 64) {
            int i = base + lane;
            int v = (i < NBUCK) ? tot[i] : 0;
            int incl = v;
#pragma unroll
            for (int d = 1; d < 64; d <<= 1) {
                int u = __shfl_up(incl, d, 64);
                if (lane >= d) incl += u;
            }
            if (i < NBUCK) bst[i] = carry + incl - v;
            carry += __shfl(incl, 63, 64);
        }
    }
    __syncthreads();
    int b = blockIdx.x * 4 + wid;
    if (b >= NBUCK) return;
    int base = bst[b];
#pragma unroll
    for (int c = 0; c < 2; ++c) {
        int idx = c * 64 + lane;
        int cv = cnt_mat[b * NBLK + idx];
        int ic = cv;
#pragma unroll
        for (int d = 1; d < 64; d <<= 1) {
            int u = __shfl_up(ic, d, 64);
            if (lane >= d) ic += u;
        }
        cnt_mat[b * NBLK + idx] = base + ic - cv;
        base += __shfl(ic, 63, 64);
    }
}

// ---------------- A1: partition edges into bucket-contiguous packed ebuf ----------------
// pack = src (16b) | dst_local (7b) << 16   (src < 50000 < 65536)
__global__ __launch_bounds__(256) void bucket_place(const int* __restrict__ ei,
                                                    const int* __restrict__ cnt_scan,
                                                    unsigned* __restrict__ ebuf)
{
    __shared__ int cur[NBUCK];
    int t = threadIdx.x, blk = blockIdx.x;
    for (int b = t; b < NBUCK; b += 256) cur[b] = cnt_scan[b * NBLK + blk];
    __syncthreads();
    int s = blk * EPB;
    for (int i = s + t; i < s + EPB; i += 256) {
        int src = ei[i], dst = ei[N_EDGES + i];
        int slot = atomicAdd(&cur[dst >> 7], 1);
        ebuf[slot] = (unsigned)src | ((unsigned)(dst & 127) << 16);
    }
}

// ---------------- fused gather (LDS int fixed-point accum) + MFMA linear ----------------
// One block per 128-dst bucket, 16 waves.
// Phase 1: edge-parallel accumulation. Per edge: 64 lanes = 64 features; one 128B
//   row load (2B/lane) + one native ds_add_u32 per lane (bank=lane&31 -> 2-way, free).
//   Fixed-point 2^20: exact integer sums -> deterministic; |sum|<2048 fits int32.
// Phase 2: the bucket's 128 nodes = 8 MFMA strips; wave w: strip w&7, out-half w>>3.
//   mean built from LDS acc (never hits global); out = [x|mean] @ W2^T + b.
__global__ __launch_bounds__(1024) void gather_mfma(const unsigned short* __restrict__ xh,
                                                    const int* __restrict__ cnt_scan,
                                                    const unsigned* __restrict__ ebuf,
                                                    const unsigned short* __restrict__ w2h,
                                                    const float* __restrict__ bl,
                                                    float* __restrict__ out)
{
    __shared__ int acc[128 * 64];                 // 32 KB
    __shared__ unsigned short wlds[128 * WLDS];   // 34.8 KB
    __shared__ int dcnt[128];
    __shared__ int range_s[2];
    int t = threadIdx.x, b = blockIdx.x;
    int lane = t & 63, w = t >> 6;                // 16 waves

    // stage weights (1024 threads x 2 chunks of 8 bf16)
#pragma unroll
    for (int c = 0; c < 2; ++c) {
        int idx = c * 1024 + t;
        int o = idx >> 4, kc = idx & 15;
        bf16x8 v = *(const bf16x8*)(w2h + o * 128 + kc * 8);
        *(bf16x8*)(&wlds[o * WLDS + kc * 8]) = v;
    }
    if (t == 0) {
        range_s[0] = cnt_scan[b * NBLK];
        range_s[1] = (b < NBUCK - 1) ? cnt_scan[(b + 1) * NBLK] : N_EDGES;
    }
#pragma unroll
    for (int i = 0; i < 8; ++i) acc[i * 1024 + t] = 0;
    if (t < 128) dcnt[t] = 0;
    __syncthreads();

    int bs = range_s[0], be = range_s[1];

    // degree histogram (native int LDS atomics)
    for (int e = bs + t; e < be; e += 1024)
        atomicAdd(&dcnt[(ebuf[e] >> 16) & 127], 1);

    // feature accumulation: wave w takes 64-edge chunks strided by 16 waves
    for (int e0 = bs + w * 64; e0 < be; e0 += 1024) {
        int m = be - e0; if (m > 64) m = 64;
        unsigned pv = (lane < m) ? ebuf[e0 + lane] : 0u;
        for (int k = 0; k < m; k += 8) {
            unsigned p[8]; int fx[8];
#pragma unroll
            for (int u = 0; u < 8; ++u) p[u] = __shfl(pv, k + u, 64);
#pragma unroll
            for (int u = 0; u < 8; ++u) {
                unsigned short hv = xh[(size_t)(p[u] & 0xFFFFu) * IN_DIM + lane];
                float f = __uint_as_float((unsigned)hv << 16);
                fx[u] = __float2int_rn(f * FIXSCALE);
            }
#pragma unroll
            for (int u = 0; u < 8; ++u)
                if (k + u < m)                     // wave-uniform guard
                    atomicAdd(&acc[((p[u] >> 16) & 127) * 64 + lane], fx[u]);
        }
    }
    __syncthreads();

    // -------- MFMA phase --------
    int s_strip = w & 7, hf = w >> 3;
    int nbase = b * 128 + s_strip * 16;
    if (nbase >= N_NODES) return;
    int row = lane & 15, q = lane >> 4;
    int nn = nbase + row;
    size_t nrow = (size_t)((nn < N_NODES) ? nn : (N_NODES - 1));

    bf16x8 a[4];
    a[0] = *(const bf16x8*)(xh + nrow * IN_DIM + q * 8);
    a[1] = *(const bf16x8*)(xh + nrow * IN_DIM + q * 8 + 32);

    int in_node = s_strip * 16 + row;
    int deg = dcnt[in_node];
    float sc = deg ? INVFIX / (float)deg : 0.0f;
    bf16x8 a2, a3;
#pragma unroll
    for (int j = 0; j < 8; ++j) {
        float f0 = (float)acc[in_node * 64 + q * 8 + j] * sc;
        float f1 = (float)acc[in_node * 64 + 32 + q * 8 + j] * sc;
        a2[j] = (short)f2bf(f0);
        a3[j] = (short)f2bf(f1);
    }
    a[2] = a2; a[3] = a3;

    f32x4 accf[4];
#pragma unroll
    for (int jj = 0; jj < 4; ++jj) accf[jj] = (f32x4){0.f, 0.f, 0.f, 0.f};

#pragma unroll
    for (int jj = 0; jj < 4; ++jj) {
        int ot = hf * 4 + jj;
        const unsigned short* wb = &wlds[(ot * 16 + row) * WLDS + q * 8];
#pragma unroll
        for (int s = 0; s < 4; ++s) {
            bf16x8 bfrag = *(const bf16x8*)(wb + s * 32);
            accf[jj] = __builtin_amdgcn_mfma_f32_16x16x32_bf16(a[s], bfrag, accf[jj], 0, 0, 0);
        }
    }

#pragma unroll
    for (int jj = 0; jj < 4; ++jj) {
        int ot = hf * 4 + jj;
        float bias = bl[ot * 16 + row];
#pragma unroll
        for (int r = 0; r < 4; ++r) {
            int n = nbase + q * 4 + r;
            if (n < N_NODES)
                out[(size_t)n * OUT_DIM + ot * 16 + row] = accf[jj][r] + bias;
        }
    }
}

extern "C" void kernel_launch(void* const* d_in, const int* in_sizes, int n_in,
                              void* d_out, int out_size, void* d_ws, size_t ws_size,
                              hipStream_t stream) {
    const float* x  = (const float*)d_in[0];
    const int*   ei = (const int*)d_in[1];
    const float* Wl = (const float*)d_in[2];
    const float* bl = (const float*)d_in[3];
    const float* Wr = (const float*)d_in[4];
    float* out = (float*)d_out;

    // ws layout (~9.9 MB):
    int*            cnt_mat = (int*)d_ws;                               // 391*128 ints
    unsigned*       ebuf    = (unsigned*)(cnt_mat + NBUCK * NBLK);      // 800000 uints
    unsigned short* xh      = (unsigned short*)(ebuf + N_EDGES);        // 3.2M bf16
    unsigned short* w2h     = xh + (size_t)N_NODES * IN_DIM;            // 16384 bf16

    bucket_count_cvt<<<NBLK, 256, 0, stream>>>(ei, x, Wl, Wr, cnt_mat, xh, w2h);
    rowscan<<<(NBUCK + 3) / 4, 256, 0, stream>>>(cnt_mat);
    bucket_place<<<NBLK, 256, 0, stream>>>(ei, cnt_mat, ebuf);
    gather_mfma<<<NBUCK, 1024, 0, stream>>>(xh, cnt_mat, ebuf, w2h, bl, out);
}